// Round 5
// baseline (389.134 us; speedup 1.0000x reference)
//
#include <hip/hip_runtime.h>

#define NI 50000
#define E_INTN 500000
#define E_BN 20000
#define E_CN 10000
#define E_TOT (E_INTN + E_BN + E_CN)

typedef __attribute__((ext_vector_type(8))) short bf16x8_t;
typedef __attribute__((ext_vector_type(4))) float f32x4_t;

__device__ __forceinline__ unsigned short f2bf(float f) {
    unsigned int u = __float_as_uint(f);
    unsigned int r = (u + 0x7FFFu + ((u >> 16) & 1u)) >> 16;
    return (unsigned short)r;
}
__device__ __forceinline__ float bf2f(unsigned int h) {
    return __uint_as_float(h << 16);
}

// async global->LDS, 16B per lane; LDS dest = wave-uniform base + lane*16
__device__ __forceinline__ void gload16(const unsigned short* g, unsigned short* l) {
    __builtin_amdgcn_global_load_lds(
        (const __attribute__((address_space(1))) void*)g,
        (__attribute__((address_space(3))) void*)l, 16, 0, 0);
}

// ---------------------------------------------------------------------------
// fused prep: input fp32->bf16 conversion, weight packing, count zeroing,
// stacked bias vectors -- all independent elementwise jobs, one dispatch.
struct WJob { const float* src; int stride, off, off2, N, K, dstOff; };
struct WJobs { WJob j[14]; };

#define CONV_NB 9375   // (2400000+255)/256 float4-groups
#define PW_NB   1792   // 14 jobs x 128 blocks
#define ZC_NB   586    // (150000+255)/256
#define PREP_NB (CONV_NB + PW_NB + ZC_NB + 1)

__global__ __launch_bounds__(256) void prep_kernel(
    const float4* __restrict__ x, const float4* __restrict__ xb,
    const float4* __restrict__ u,
    ushort4* __restrict__ x_bf, ushort4* __restrict__ xb_bf,
    ushort4* __restrict__ u_bf,
    WJobs jobs, unsigned short* __restrict__ wbuf,
    int* __restrict__ cnts,
    const float* __restrict__ b_ii, const float* __restrict__ b_bi,
    const float* __restrict__ b_ci, const float* __restrict__ b_bb,
    const float* __restrict__ b_cc, float* __restrict__ bias) {
    int b = blockIdx.x;
    int tid = threadIdx.x;
    if (b < CONV_NB) {
        int g = b * 256 + tid;
        const float4* src; ushort4* dst; int i;
        if (g < 1600000)      { src = x;  dst = x_bf;  i = g; }
        else if (g < 2240000) { src = xb; dst = xb_bf; i = g - 1600000; }
        else if (g < 2400000) { src = u;  dst = u_bf;  i = g - 2240000; }
        else return;
        float4 v = src[i];
        ushort4 o;
        o.x = f2bf(v.x); o.y = f2bf(v.y); o.z = f2bf(v.z); o.w = f2bf(v.w);
        dst[i] = o;
    } else if (b < CONV_NB + PW_NB) {
        int lb = b - CONV_NB;
        WJob jb = jobs.j[lb >> 7];
        int idx = (lb & 127) * 256 + tid;
        if (idx >= jb.N * jb.K) return;
        int n = idx / jb.K;
        int k = idx - n * jb.K;
        float v = jb.src[(size_t)n * jb.stride + jb.off + k];
        if (jb.off2 >= 0) v += jb.src[(size_t)n * jb.stride + jb.off2 + k];
        wbuf[jb.dstOff + (size_t)n * jb.K + k] = f2bf(v);
    } else if (b < CONV_NB + PW_NB + ZC_NB) {
        int i = (b - CONV_NB - PW_NB) * 256 + tid;
        if (i < 3 * NI) cnts[i] = 0;
    } else {
        int t = tid;  // 256 threads cover 1024 via 4 strided steps
        for (int s = 0; s < 4; ++s, t += 256) {
            if (t < 512) {
                float v = 0.f;
                if (t >= 384) v = b_ci[t - 384];
                else if (t >= 256) v = b_bi[t - 256];
                else if (t >= 128) v = b_ii[t - 128];
                bias[t] = v;
            } else if (t < 768) {
                int c = t - 512;
                bias[512 + c] = (c < 128) ? 0.f : b_bb[c - 128];
            } else {
                int c = t - 768;
                bias[768 + c] = (c < 128) ? 0.f : b_cc[c - 128];
            }
        }
    }
}

// ---------------------------------------------------------------------------
__global__ __launch_bounds__(256) void count_kernel(const int* __restrict__ ei,
                                                    const int* __restrict__ eb,
                                                    const int* __restrict__ ec,
                                                    const int* __restrict__ bidx,
                                                    const int* __restrict__ cidx,
                                                    int* __restrict__ ci,
                                                    int* __restrict__ cb,
                                                    int* __restrict__ cc) {
    int e = blockIdx.x * 256 + threadIdx.x;
    if (e < E_INTN) {
        atomicAdd(&ci[ei[E_INTN + e]], 1);
    } else if (e < E_INTN + E_BN) {
        int j = e - E_INTN;
        int s = eb[j];
        bool m = false;
#pragma unroll
        for (int k = 0; k < 16; ++k) m = m || (s == bidx[k]);
        if (m) atomicAdd(&cb[eb[E_BN + j]], 1);
    } else if (e < E_TOT) {
        int j = e - E_INTN - E_BN;
        int s = ec[j];
        bool m = false;
#pragma unroll
        for (int k = 0; k < 16; ++k) m = m || (s == cidx[k]);
        if (m) atomicAdd(&cc[ec[E_CN + j]], 1);
    }
}

// ---------------------------------------------------------------------------
#define SCAN_NB 196   // ceil(50000/256)

__global__ __launch_bounds__(256) void scan1_kernel(const int* __restrict__ ci,
                                                    const int* __restrict__ cb,
                                                    const int* __restrict__ cc,
                                                    int* __restrict__ bsum) {
    __shared__ int sm[256];
    int n = blockIdx.x * 256 + threadIdx.x;
    int d = (n < NI) ? ci[n] + cb[n] + cc[n] : 0;
    sm[threadIdx.x] = d;
    __syncthreads();
    for (int s = 128; s > 0; s >>= 1) {
        if (threadIdx.x < s) sm[threadIdx.x] += sm[threadIdx.x + s];
        __syncthreads();
    }
    if (threadIdx.x == 0) bsum[blockIdx.x] = sm[0];
}

__global__ __launch_bounds__(256) void scan2_kernel(const int* __restrict__ bsum,
                                                    int* __restrict__ ebase) {
    __shared__ int sm[256];
    int t = threadIdx.x;
    sm[t] = (t < SCAN_NB) ? bsum[t] : 0;
    __syncthreads();
    for (int d = 1; d < 256; d <<= 1) {
        int v = (t >= d) ? sm[t - d] : 0;
        __syncthreads();
        sm[t] += v;
        __syncthreads();
    }
    ebase[t] = (t > 0) ? sm[t - 1] : 0;
}

__global__ __launch_bounds__(256) void scan3_kernel(const int* __restrict__ ci,
                                                    const int* __restrict__ cb,
                                                    const int* __restrict__ cc,
                                                    const int* __restrict__ ebase,
                                                    int* __restrict__ offsets,
                                                    int* __restrict__ cursor) {
    __shared__ int sm[256];
    int t = threadIdx.x;
    int n = blockIdx.x * 256 + t;
    int d = (n < NI) ? ci[n] + cb[n] + cc[n] : 0;
    sm[t] = d;
    __syncthreads();
    for (int dd = 1; dd < 256; dd <<= 1) {
        int v = (t >= dd) ? sm[t - dd] : 0;
        __syncthreads();
        sm[t] += v;
        __syncthreads();
    }
    if (n < NI) {
        int excl = sm[t] - d + ebase[blockIdx.x];
        offsets[n] = excl;
        cursor[n] = excl;
    }
}

// ---------------------------------------------------------------------------
__global__ __launch_bounds__(256) void fill_kernel(const int* __restrict__ ei,
                                                   const int* __restrict__ eb,
                                                   const int* __restrict__ ec,
                                                   const int* __restrict__ bidx,
                                                   const int* __restrict__ cidx,
                                                   int* __restrict__ cursor,
                                                   int* __restrict__ eids) {
    int e = blockIdx.x * 256 + threadIdx.x;
    int t, payload;
    if (e < E_INTN) {
        t = ei[E_INTN + e];
        payload = ei[e];
    } else if (e < E_INTN + E_BN) {
        int j = e - E_INTN;
        int s = eb[j];
        bool m = false;
#pragma unroll
        for (int k = 0; k < 16; ++k) m = m || (s == bidx[k]);
        if (!m) return;
        t = eb[E_BN + j];
        payload = NI + j;
    } else if (e < E_TOT) {
        int j = e - E_INTN - E_BN;
        int s = ec[j];
        bool m = false;
#pragma unroll
        for (int k = 0; k < 16; ++k) m = m || (s == cidx[k]);
        if (!m) return;
        t = ec[E_CN + j];
        payload = NI + E_BN + j;
    } else {
        return;
    }
    int idx = atomicAdd(&cursor[t], 1);
    eids[idx] = payload;
}

// ---------------------------------------------------------------------------
// gather: ONE WAVE (64 lanes) per node, 1 uint (2 bf16) per lane.
// deg-loop is wave-uniform (no divergence); each edge-row read = one
// coalesced 256B transaction; eid load is a same-address broadcast.
__global__ __launch_bounds__(256) void gather_kernel(
    const unsigned short* __restrict__ Yx,
    const unsigned short* __restrict__ Yxb,
    const unsigned short* __restrict__ Yu,
    const int* __restrict__ offsets,
    const int* __restrict__ ci, const int* __restrict__ cb,
    const int* __restrict__ cc, const int* __restrict__ eids,
    unsigned short* __restrict__ agg) {
    int g = blockIdx.x * 256 + threadIdx.x;
    int n = g >> 6;
    int lane = g & 63;
    if (n >= NI) return;
    int off = offsets[n];
    int di = ci[n], db = cb[n], dc = cc[n];
    int deg = di + db + dc;
    float fi = (float)di, fb = (float)db, fc = (float)dc;
    const unsigned int* yrow = (const unsigned int*)(Yx + (size_t)n * 512);
    unsigned int vi = yrow[64 + lane];
    unsigned int vb = yrow[128 + lane];
    unsigned int vc = yrow[192 + lane];
    float a0 = fi * bf2f(vi & 0xffff) + fb * bf2f(vb & 0xffff) + fc * bf2f(vc & 0xffff);
    float a1 = fi * bf2f(vi >> 16)    + fb * bf2f(vb >> 16)    + fc * bf2f(vc >> 16);
    for (int k = 0; k < deg; ++k) {
        int eid = eids[off + k];
        const unsigned int* row =
            (eid < NI) ? (const unsigned int*)(Yx + (size_t)eid * 512)
          : (eid < NI + E_BN) ? (const unsigned int*)(Yxb + (size_t)(eid - NI) * 256)
          : (const unsigned int*)(Yu + (size_t)(eid - NI - E_BN) * 256);
        unsigned int d = row[lane];
        a0 += bf2f(d & 0xffff);
        a1 += bf2f(d >> 16);
    }
    float inv = 1.f / fmaxf((float)deg, 1.f);
    ((unsigned int*)agg)[(size_t)n * 64 + lane] =
        (unsigned)f2bf(a0 * inv) | ((unsigned)f2bf(a1 * inv) << 16);
}

// ---------------------------------------------------------------------------
// bf16 MFMA GEMM with global_load_lds(16B) staging (m97 structure).
// C[M,N] = A1@W1.T (+ A2@W2.T) + b1 + b2, opt bf16 output.
// A row-major bf16 (stride lda), W packed [N x K] bf16. 128x128 block tile,
// BK=32, unpadded LDS (contiguity required by global_load_lds), 4 waves,
// 4x4 MFMA tiles. N multiple of 128; K multiple of 32; M >= 128.
__global__ __launch_bounds__(256) void mfma_gemm_kernel(
    const unsigned short* __restrict__ A1, int lda1, int K1,
    const unsigned short* __restrict__ W1,
    const unsigned short* __restrict__ A2, int lda2, int K2,
    const unsigned short* __restrict__ W2,
    const float* __restrict__ b1, const float* __restrict__ b2,
    int outbf, void* __restrict__ C, int M, int ldc) {
    __shared__ __align__(16) unsigned short As[128 * 32];
    __shared__ __align__(16) unsigned short Wsh[128 * 32];

    const int m0 = blockIdx.x * 128;
    const int n0 = blockIdx.y * 128;
    const int tid = threadIdx.x;
    const int wv = tid >> 6;
    const int wm = wv >> 1, wn = wv & 1;
    const int lane = tid & 63;
    const int lr = lane & 15;
    const int k0 = (lane >> 4) * 8;

    f32x4_t acc[4][4];
#pragma unroll
    for (int i = 0; i < 4; ++i)
#pragma unroll
        for (int j = 0; j < 4; ++j) {
            f32x4_t z = {0.f, 0.f, 0.f, 0.f};
            acc[i][j] = z;
        }

    for (int pass = 0; pass < 2; ++pass) {
        const unsigned short* Ap = (pass == 0) ? A1 : A2;
        if (Ap == nullptr) break;
        const unsigned short* Wp = (pass == 0) ? W1 : W2;
        const int lda = (pass == 0) ? lda1 : lda2;
        const int K   = (pass == 0) ? K1 : K2;
        const int nch = K >> 5;

        for (int c = 0; c < nch; ++c) {
            const int kb = c * 32;
            __syncthreads();   // prior chunk's frags consumed
#pragma unroll
            for (int p = 0; p < 2; ++p) {
                int s = p * 256 + tid;        // 16B slot index, 0..511
                int r = s >> 2;               // tile row (4 slots/row of 64B)
                int c8 = (s & 3) * 8;         // element offset within row
                int m = m0 + r;
                if (m >= M) m = M - 1;
                int ldsbase = (p * 256 + wv * 64) * 8;   // wave-uniform, ushorts
                gload16(Ap + (size_t)m * lda + kb + c8, &As[ldsbase]);
                gload16(Wp + (size_t)(n0 + r) * K + kb + c8, &Wsh[ldsbase]);
            }
            __syncthreads();   // drains vmcnt before barrier

            bf16x8_t af[4], wf[4];
#pragma unroll
            for (int i = 0; i < 4; ++i)
                af[i] = *(const bf16x8_t*)&As[(wm * 64 + i * 16 + lr) * 32 + k0];
#pragma unroll
            for (int j = 0; j < 4; ++j)
                wf[j] = *(const bf16x8_t*)&Wsh[(wn * 64 + j * 16 + lr) * 32 + k0];
#pragma unroll
            for (int i = 0; i < 4; ++i)
#pragma unroll
                for (int j = 0; j < 4; ++j)
                    acc[i][j] = __builtin_amdgcn_mfma_f32_16x16x32_bf16(
                        af[i], wf[j], acc[i][j], 0, 0, 0);
        }
    }

    const int lq = lane >> 4;
#pragma unroll
    for (int j = 0; j < 4; ++j) {
        int col = n0 + wn * 64 + j * 16 + lr;
        float bj = 0.f;
        if (b1) bj += b1[col];
        if (b2) bj += b2[col];
#pragma unroll
        for (int i = 0; i < 4; ++i) {
            int rowBase = m0 + wm * 64 + i * 16 + lq * 4;
#pragma unroll
            for (int r = 0; r < 4; ++r) {
                int gm = rowBase + r;
                if (gm >= M) continue;
                float v = acc[i][j][r] + bj;
                if (outbf) {
                    ((unsigned short*)C)[(size_t)gm * ldc + col] = f2bf(v);
                } else {
                    ((float*)C)[(size_t)gm * ldc + col] = v;
                }
            }
        }
    }
}

// ---------------------------------------------------------------------------
extern "C" void kernel_launch(void* const* d_in, const int* in_sizes, int n_in,
                              void* d_out, int out_size, void* d_ws, size_t ws_size,
                              hipStream_t stream) {
    const float* x    = (const float*)d_in[0];
    const float* xb   = (const float*)d_in[1];
    const float* u    = (const float*)d_in[2];
    const int*   ei   = (const int*)d_in[3];
    const int*   eb   = (const int*)d_in[4];
    const int*   ec   = (const int*)d_in[5];
    const int*   bidx = (const int*)d_in[6];
    const int*   cidx = (const int*)d_in[7];
    const float* W_ii = (const float*)d_in[8];   const float* b_ii = (const float*)d_in[9];
    const float* W_bi = (const float*)d_in[10];  const float* b_bi = (const float*)d_in[11];
    const float* W_ci = (const float*)d_in[12];  const float* b_ci = (const float*)d_in[13];
    const float* W_bb = (const float*)d_in[14];  const float* b_bb = (const float*)d_in[15];
    const float* W_cc = (const float*)d_in[16];  const float* b_cc = (const float*)d_in[17];
    const float* W_im = (const float*)d_in[18];  const float* b_im = (const float*)d_in[19];
    const float* W_is = (const float*)d_in[20];  const float* b_is = (const float*)d_in[21];
    const float* W_bm = (const float*)d_in[22];  const float* b_bm = (const float*)d_in[23];
    const float* W_bs = (const float*)d_in[24];  const float* b_bs = (const float*)d_in[25];
    const float* W_cm = (const float*)d_in[26];  const float* b_cm = (const float*)d_in[27];
    const float* W_cs = (const float*)d_in[28];  const float* b_cs = (const float*)d_in[29];

    float* out = (float*)d_out;
    unsigned short* bfr = (unsigned short*)d_ws;

    // ---- ws layout (ushort offsets); total ~99.3 MB ----
    unsigned short* x_bf  = bfr;                 //  6,400,000
    unsigned short* xb_bf = bfr + 6400000;       //  2,560,000
    unsigned short* u_bf  = bfr + 8960000;       //    640,000
    unsigned short* Yx    = bfr + 9600000;       // 25,600,000  [50000 x 512]
    unsigned short* Yxb   = bfr + 35200000;      //  5,120,000  [20000 x 256]
    unsigned short* Yu    = bfr + 40320000;      //  2,560,000  [10000 x 256]
    unsigned short* agg   = bfr + 42880000;      //  6,400,000  [50000 x 128]
    unsigned short* wbuf  = bfr + 49280000;      //    294,912
    float* bias  = (float*)(bfr + 49600000);     //  1024 fp32
    float* bias_x  = bias;
    float* bias_xb = bias + 512;
    float* bias_u  = bias + 768;

    enum {
        O_WX  = 0,       O_WXB = 65536,  O_WU  = 98304,
        O_wis = 114688,  O_wim = 147456, O_wbs = 180224,
        O_wbm = 212992,  O_wcs = 245760, O_wcm = 262144
    };

    // ---- int scratch in d_out boundary region (overwritten by final GEMM) ----
    int* I       = (int*)(out + (size_t)NI * 256);
    int* ci      = I;
    int* cb      = I + 50000;
    int* cc      = I + 100000;
    int* offsets = I + 150000;
    int* cursor  = I + 200000;
    int* bsum    = I + 250000;   // 256
    int* ebase   = I + 250256;   // 256
    int* eids    = I + 250512;   // 530000

    // ---- 1. fused prep (conv + weight pack + zero counts + bias) ----
    WJobs JB;
    auto setj = [&](int i, const float* s, int st, int o, int o2, int N, int K, int d) {
        JB.j[i].src = s; JB.j[i].stride = st; JB.j[i].off = o; JB.j[i].off2 = o2;
        JB.j[i].N = N; JB.j[i].K = K; JB.j[i].dstOff = d;
    };
    setj(0,  W_ii, 256, 0,   -1, 128, 128, O_WX);           // A slice
    setj(1,  W_ii, 256, 128, -1, 128, 128, O_WX + 16384);   // Bii
    setj(2,  W_bi, 256, 128, -1, 128, 128, O_WX + 32768);   // Bbi
    setj(3,  W_ci, 192, 64,  -1, 128, 128, O_WX + 49152);   // Bci
    setj(4,  W_bi, 256, 0,   -1, 128, 128, O_WXB);          // xbp
    setj(5,  W_bb, 256, 0,  128, 128, 128, O_WXB + 16384);  // sb (A+B)
    setj(6,  W_ci, 192, 0,   -1, 128, 64,  O_WU);           // ucp
    setj(7,  W_cc, 128, 0,   64, 128, 64,  O_WU + 8192);    // sc (A+B)
    setj(8,  W_is, 128, 0,   -1, 256, 128, O_wis);
    setj(9,  W_im, 128, 0,   -1, 256, 128, O_wim);
    setj(10, W_bs, 128, 0,   -1, 256, 128, O_wbs);
    setj(11, W_bm, 128, 0,   -1, 256, 128, O_wbm);
    setj(12, W_cs, 64,  0,   -1, 256, 64,  O_wcs);
    setj(13, W_cm, 128, 0,   -1, 256, 128, O_wcm);
    prep_kernel<<<dim3(PREP_NB), dim3(256), 0, stream>>>(
        (const float4*)x, (const float4*)xb, (const float4*)u,
        (ushort4*)x_bf, (ushort4*)xb_bf, (ushort4*)u_bf,
        JB, wbuf, ci, b_ii, b_bi, b_ci, b_bb, b_cc, bias);

    // ---- 2. counts + parallel scan + CSR fill ----
    count_kernel<<<dim3((E_TOT + 255) / 256), dim3(256), 0, stream>>>(
        ei, eb, ec, bidx, cidx, ci, cb, cc);
    scan1_kernel<<<dim3(SCAN_NB), dim3(256), 0, stream>>>(ci, cb, cc, bsum);
    scan2_kernel<<<dim3(1), dim3(256), 0, stream>>>(bsum, ebase);
    scan3_kernel<<<dim3(SCAN_NB), dim3(256), 0, stream>>>(ci, cb, cc, ebase,
                                                          offsets, cursor);
    fill_kernel<<<dim3((E_TOT + 255) / 256), dim3(256), 0, stream>>>(
        ei, eb, ec, bidx, cidx, cursor, eids);

    auto G = [&](const unsigned short* A1, int lda1, int K1, const unsigned short* W1,
                 const unsigned short* A2, int lda2, int K2, const unsigned short* W2,
                 const float* bb1, const float* bb2, int outbf,
                 void* C, int M, int N, int ldc) {
        mfma_gemm_kernel<<<dim3((M + 127) / 128, N / 128), dim3(256), 0, stream>>>(
            A1, lda1, K1, W1, A2, lda2, K2, W2, bb1, bb2, outbf, C, M, ldc);
    };

    // ---- 3. stacked forward GEMMs (biases folded per-column) ----
    G(x_bf, 128, 128, wbuf + O_WX, nullptr, 0, 0, nullptr,
      bias_x, nullptr, 1, Yx, NI, 512, 512);
    G(xb_bf, 128, 128, wbuf + O_WXB, nullptr, 0, 0, nullptr,
      bias_xb, nullptr, 1, Yxb, E_BN, 256, 256);
    G(u_bf, 64, 64, wbuf + O_WU, nullptr, 0, 0, nullptr,
      bias_u, nullptr, 1, Yu, E_CN, 256, 256);

    // ---- 4. gather: base from Y slices + CSR edge rows -> agg bf16 ----
    gather_kernel<<<dim3((NI * 64 + 255) / 256), dim3(256), 0, stream>>>(
        Yx, Yxb, Yu, offsets, ci, cb, cc, eids, agg);

    // ---- 5. final GEMMs ----
    G(x_bf, 128, 128, wbuf + O_wis, agg, 128, 128, wbuf + O_wim,
      b_is, b_im, 0, out, NI, 256, 256);
    G(xb_bf, 128, 128, wbuf + O_wbs, Yxb + 128, 256, 128, wbuf + O_wbm,
      b_bs, b_bm, 0, out + (size_t)NI * 256, E_BN, 256, 256);
    G(u_bf, 64, 64, wbuf + O_wcs, Yu + 128, 256, 128, wbuf + O_wcm,
      b_cs, b_cm, 0, out + (size_t)(NI + E_BN) * 256, E_CN, 256, 256);
}

// Round 6
// 356.075 us; speedup vs baseline: 1.0928x; 1.0928x over previous
//
#include <hip/hip_runtime.h>

#define NI 50000
#define E_INTN 500000
#define E_BN 20000
#define E_CN 10000
#define E_TOT (E_INTN + E_BN + E_CN)

typedef __attribute__((ext_vector_type(8))) short bf16x8_t;
typedef __attribute__((ext_vector_type(4))) float f32x4_t;

__device__ __forceinline__ unsigned short f2bf(float f) {
    unsigned int u = __float_as_uint(f);
    unsigned int r = (u + 0x7FFFu + ((u >> 16) & 1u)) >> 16;
    return (unsigned short)r;
}
__device__ __forceinline__ float bf2f(unsigned int h) {
    return __uint_as_float(h << 16);
}

// async global->LDS, 16B per lane; LDS dest = wave-uniform base + lane*16
__device__ __forceinline__ void gload16(const unsigned short* g, unsigned short* l) {
    __builtin_amdgcn_global_load_lds(
        (const __attribute__((address_space(1))) void*)g,
        (__attribute__((address_space(3))) void*)l, 16, 0, 0);
}

// ---------------------------------------------------------------------------
// fused prep: input fp32->bf16 conversion, weight packing, count zeroing,
// stacked bias vectors -- all independent elementwise jobs, one dispatch.
struct WJob { const float* src; int stride, off, off2, N, K, dstOff; };
struct WJobs { WJob j[14]; };

#define CONV_NB 9375   // (2400000+255)/256 float4-groups
#define PW_NB   1792   // 14 jobs x 128 blocks
#define ZC_NB   586    // (150000+255)/256
#define PREP_NB (CONV_NB + PW_NB + ZC_NB + 1)

__global__ __launch_bounds__(256) void prep_kernel(
    const float4* __restrict__ x, const float4* __restrict__ xb,
    const float4* __restrict__ u,
    ushort4* __restrict__ x_bf, ushort4* __restrict__ xb_bf,
    ushort4* __restrict__ u_bf,
    WJobs jobs, unsigned short* __restrict__ wbuf,
    int* __restrict__ cnts,
    const float* __restrict__ b_ii, const float* __restrict__ b_bi,
    const float* __restrict__ b_ci, const float* __restrict__ b_bb,
    const float* __restrict__ b_cc, float* __restrict__ bias) {
    int b = blockIdx.x;
    int tid = threadIdx.x;
    if (b < CONV_NB) {
        int g = b * 256 + tid;
        const float4* src; ushort4* dst; int i;
        if (g < 1600000)      { src = x;  dst = x_bf;  i = g; }
        else if (g < 2240000) { src = xb; dst = xb_bf; i = g - 1600000; }
        else if (g < 2400000) { src = u;  dst = u_bf;  i = g - 2240000; }
        else return;
        float4 v = src[i];
        ushort4 o;
        o.x = f2bf(v.x); o.y = f2bf(v.y); o.z = f2bf(v.z); o.w = f2bf(v.w);
        dst[i] = o;
    } else if (b < CONV_NB + PW_NB) {
        int lb = b - CONV_NB;
        WJob jb = jobs.j[lb >> 7];
        int idx = (lb & 127) * 256 + tid;
        if (idx >= jb.N * jb.K) return;
        int n = idx / jb.K;
        int k = idx - n * jb.K;
        float v = jb.src[(size_t)n * jb.stride + jb.off + k];
        if (jb.off2 >= 0) v += jb.src[(size_t)n * jb.stride + jb.off2 + k];
        wbuf[jb.dstOff + (size_t)n * jb.K + k] = f2bf(v);
    } else if (b < CONV_NB + PW_NB + ZC_NB) {
        int i = (b - CONV_NB - PW_NB) * 256 + tid;
        if (i < 3 * NI) cnts[i] = 0;
    } else {
        int t = tid;
        for (int s = 0; s < 4; ++s, t += 256) {
            if (t < 512) {
                float v = 0.f;
                if (t >= 384) v = b_ci[t - 384];
                else if (t >= 256) v = b_bi[t - 256];
                else if (t >= 128) v = b_ii[t - 128];
                bias[t] = v;
            } else if (t < 768) {
                int c = t - 512;
                bias[512 + c] = (c < 128) ? 0.f : b_bb[c - 128];
            } else {
                int c = t - 768;
                bias[768 + c] = (c < 128) ? 0.f : b_cc[c - 128];
            }
        }
    }
}

// ---------------------------------------------------------------------------
__global__ __launch_bounds__(256) void count_kernel(const int* __restrict__ ei,
                                                    const int* __restrict__ eb,
                                                    const int* __restrict__ ec,
                                                    const int* __restrict__ bidx,
                                                    const int* __restrict__ cidx,
                                                    int* __restrict__ ci,
                                                    int* __restrict__ cb,
                                                    int* __restrict__ cc) {
    int e = blockIdx.x * 256 + threadIdx.x;
    if (e < E_INTN) {
        atomicAdd(&ci[ei[E_INTN + e]], 1);
    } else if (e < E_INTN + E_BN) {
        int j = e - E_INTN;
        int s = eb[j];
        bool m = false;
#pragma unroll
        for (int k = 0; k < 16; ++k) m = m || (s == bidx[k]);
        if (m) atomicAdd(&cb[eb[E_BN + j]], 1);
    } else if (e < E_TOT) {
        int j = e - E_INTN - E_BN;
        int s = ec[j];
        bool m = false;
#pragma unroll
        for (int k = 0; k < 16; ++k) m = m || (s == cidx[k]);
        if (m) atomicAdd(&cc[ec[E_CN + j]], 1);
    }
}

// ---------------------------------------------------------------------------
#define SCAN_NB 196   // ceil(50000/256)

__global__ __launch_bounds__(256) void scan1_kernel(const int* __restrict__ ci,
                                                    const int* __restrict__ cb,
                                                    const int* __restrict__ cc,
                                                    int* __restrict__ bsum) {
    __shared__ int sm[256];
    int n = blockIdx.x * 256 + threadIdx.x;
    int d = (n < NI) ? ci[n] + cb[n] + cc[n] : 0;
    sm[threadIdx.x] = d;
    __syncthreads();
    for (int s = 128; s > 0; s >>= 1) {
        if (threadIdx.x < s) sm[threadIdx.x] += sm[threadIdx.x + s];
        __syncthreads();
    }
    if (threadIdx.x == 0) bsum[blockIdx.x] = sm[0];
}

__global__ __launch_bounds__(256) void scan2_kernel(const int* __restrict__ bsum,
                                                    int* __restrict__ ebase) {
    __shared__ int sm[256];
    int t = threadIdx.x;
    sm[t] = (t < SCAN_NB) ? bsum[t] : 0;
    __syncthreads();
    for (int d = 1; d < 256; d <<= 1) {
        int v = (t >= d) ? sm[t - d] : 0;
        __syncthreads();
        sm[t] += v;
        __syncthreads();
    }
    ebase[t] = (t > 0) ? sm[t - 1] : 0;
}

__global__ __launch_bounds__(256) void scan3_kernel(const int* __restrict__ ci,
                                                    const int* __restrict__ cb,
                                                    const int* __restrict__ cc,
                                                    const int* __restrict__ ebase,
                                                    int* __restrict__ offsets,
                                                    int* __restrict__ cursor) {
    __shared__ int sm[256];
    int t = threadIdx.x;
    int n = blockIdx.x * 256 + t;
    int d = (n < NI) ? ci[n] + cb[n] + cc[n] : 0;
    sm[t] = d;
    __syncthreads();
    for (int dd = 1; dd < 256; dd <<= 1) {
        int v = (t >= dd) ? sm[t - dd] : 0;
        __syncthreads();
        sm[t] += v;
        __syncthreads();
    }
    if (n < NI) {
        int excl = sm[t] - d + ebase[blockIdx.x];
        offsets[n] = excl;
        cursor[n] = excl;
    }
}

// ---------------------------------------------------------------------------
__global__ __launch_bounds__(256) void fill_kernel(const int* __restrict__ ei,
                                                   const int* __restrict__ eb,
                                                   const int* __restrict__ ec,
                                                   const int* __restrict__ bidx,
                                                   const int* __restrict__ cidx,
                                                   int* __restrict__ cursor,
                                                   int* __restrict__ eids) {
    int e = blockIdx.x * 256 + threadIdx.x;
    int t, payload;
    if (e < E_INTN) {
        t = ei[E_INTN + e];
        payload = ei[e];
    } else if (e < E_INTN + E_BN) {
        int j = e - E_INTN;
        int s = eb[j];
        bool m = false;
#pragma unroll
        for (int k = 0; k < 16; ++k) m = m || (s == bidx[k]);
        if (!m) return;
        t = eb[E_BN + j];
        payload = NI + j;
    } else if (e < E_TOT) {
        int j = e - E_INTN - E_BN;
        int s = ec[j];
        bool m = false;
#pragma unroll
        for (int k = 0; k < 16; ++k) m = m || (s == cidx[k]);
        if (!m) return;
        t = ec[E_CN + j];
        payload = NI + E_BN + j;
    } else {
        return;
    }
    int idx = atomicAdd(&cursor[t], 1);
    eids[idx] = payload;
}

// ---------------------------------------------------------------------------
// gather: 16 lanes/node (4 nodes/wave), uint4 (8 bf16) per lane.
// k-loop unrolled x4 with batched eid loads -> 4 rows (16 per wave) in
// flight: MLP-bound, not latency-bound (round-5 lesson).
__device__ __forceinline__ const unsigned short* row_ptr(
    int eid, const unsigned short* Yx, const unsigned short* Yxb,
    const unsigned short* Yu) {
    return (eid < NI) ? Yx + (size_t)eid * 512
         : (eid < NI + E_BN) ? Yxb + (size_t)(eid - NI) * 256
         : Yu + (size_t)(eid - NI - E_BN) * 256;
}

__device__ __forceinline__ void acc_row(float* acc, uint4 d) {
    acc[0] += bf2f(d.x & 0xffff); acc[1] += bf2f(d.x >> 16);
    acc[2] += bf2f(d.y & 0xffff); acc[3] += bf2f(d.y >> 16);
    acc[4] += bf2f(d.z & 0xffff); acc[5] += bf2f(d.z >> 16);
    acc[6] += bf2f(d.w & 0xffff); acc[7] += bf2f(d.w >> 16);
}

__global__ __launch_bounds__(256) void gather_kernel(
    const unsigned short* __restrict__ Yx,
    const unsigned short* __restrict__ Yxb,
    const unsigned short* __restrict__ Yu,
    const int* __restrict__ offsets,
    const int* __restrict__ ci, const int* __restrict__ cb,
    const int* __restrict__ cc, const int* __restrict__ eids,
    unsigned short* __restrict__ agg) {
    int g = blockIdx.x * 256 + threadIdx.x;
    int n = g >> 4;
    int lane = g & 15;
    if (n >= NI) return;
    int off = offsets[n];
    int di = ci[n], db = cb[n], dc = cc[n];
    int deg = di + db + dc;
    float fi = (float)di, fb = (float)db, fc = (float)dc;
    const unsigned short* yrow = Yx + (size_t)n * 512 + lane * 8;
    uint4 vi = *(const uint4*)(yrow + 128);
    uint4 vb = *(const uint4*)(yrow + 256);
    uint4 vc = *(const uint4*)(yrow + 384);
    float acc[8];
    acc[0] = fi * bf2f(vi.x & 0xffff) + fb * bf2f(vb.x & 0xffff) + fc * bf2f(vc.x & 0xffff);
    acc[1] = fi * bf2f(vi.x >> 16)    + fb * bf2f(vb.x >> 16)    + fc * bf2f(vc.x >> 16);
    acc[2] = fi * bf2f(vi.y & 0xffff) + fb * bf2f(vb.y & 0xffff) + fc * bf2f(vc.y & 0xffff);
    acc[3] = fi * bf2f(vi.y >> 16)    + fb * bf2f(vb.y >> 16)    + fc * bf2f(vc.y >> 16);
    acc[4] = fi * bf2f(vi.z & 0xffff) + fb * bf2f(vb.z & 0xffff) + fc * bf2f(vc.z & 0xffff);
    acc[5] = fi * bf2f(vi.z >> 16)    + fb * bf2f(vb.z >> 16)    + fc * bf2f(vc.z >> 16);
    acc[6] = fi * bf2f(vi.w & 0xffff) + fb * bf2f(vb.w & 0xffff) + fc * bf2f(vc.w & 0xffff);
    acc[7] = fi * bf2f(vi.w >> 16)    + fb * bf2f(vb.w >> 16)    + fc * bf2f(vc.w >> 16);
    int k = 0;
    for (; k + 4 <= deg; k += 4) {
        int e0 = eids[off + k],     e1 = eids[off + k + 1];
        int e2 = eids[off + k + 2], e3 = eids[off + k + 3];
        const unsigned short* r0 = row_ptr(e0, Yx, Yxb, Yu);
        const unsigned short* r1 = row_ptr(e1, Yx, Yxb, Yu);
        const unsigned short* r2 = row_ptr(e2, Yx, Yxb, Yu);
        const unsigned short* r3 = row_ptr(e3, Yx, Yxb, Yu);
        uint4 d0 = *(const uint4*)(r0 + lane * 8);
        uint4 d1 = *(const uint4*)(r1 + lane * 8);
        uint4 d2 = *(const uint4*)(r2 + lane * 8);
        uint4 d3 = *(const uint4*)(r3 + lane * 8);
        acc_row(acc, d0); acc_row(acc, d1); acc_row(acc, d2); acc_row(acc, d3);
    }
    for (; k < deg; ++k) {
        const unsigned short* r0 = row_ptr(eids[off + k], Yx, Yxb, Yu);
        acc_row(acc, *(const uint4*)(r0 + lane * 8));
    }
    float inv = 1.f / fmaxf((float)deg, 1.f);
    uint4 o;
    o.x = (unsigned)f2bf(acc[0] * inv) | ((unsigned)f2bf(acc[1] * inv) << 16);
    o.y = (unsigned)f2bf(acc[2] * inv) | ((unsigned)f2bf(acc[3] * inv) << 16);
    o.z = (unsigned)f2bf(acc[4] * inv) | ((unsigned)f2bf(acc[5] * inv) << 16);
    o.w = (unsigned)f2bf(acc[6] * inv) | ((unsigned)f2bf(acc[7] * inv) << 16);
    *(uint4*)(agg + (size_t)n * 128 + lane * 8) = o;
}

// ---------------------------------------------------------------------------
// bf16 MFMA GEMM, global_load_lds(16B) staging + XOR chunk swizzle.
// LDS slot (r, kq) stores global chunk kq ^ (r&3) ^ ((r>>2)&3): fragment
// ds_read_b128 quads then hit all 32 banks exactly 2-way (free, m136);
// staging stays 16B/lane within each row's 64B segment (coalesced).
// C[M,N] = A1@W1.T (+ A2@W2.T) + b1 + b2, opt bf16 out. 128x128 tile, BK=32.
__global__ __launch_bounds__(256) void mfma_gemm_kernel(
    const unsigned short* __restrict__ A1, int lda1, int K1,
    const unsigned short* __restrict__ W1,
    const unsigned short* __restrict__ A2, int lda2, int K2,
    const unsigned short* __restrict__ W2,
    const float* __restrict__ b1, const float* __restrict__ b2,
    int outbf, void* __restrict__ C, int M, int ldc) {
    __shared__ __align__(16) unsigned short As[128 * 32];
    __shared__ __align__(16) unsigned short Wsh[128 * 32];

    const int m0 = blockIdx.x * 128;
    const int n0 = blockIdx.y * 128;
    const int tid = threadIdx.x;
    const int wv = tid >> 6;
    const int wm = wv >> 1, wn = wv & 1;
    const int lane = tid & 63;
    const int lr = lane & 15;
    const int kq_g = lane >> 4;                       // global k-chunk 0..3
    const int qlr = (lr & 3) ^ ((lr >> 2) & 3);       // row-swizzle key
    const int kslot = (kq_g ^ qlr) * 8;               // LDS chunk (ushorts)

    f32x4_t acc[4][4];
#pragma unroll
    for (int i = 0; i < 4; ++i)
#pragma unroll
        for (int j = 0; j < 4; ++j) {
            f32x4_t z = {0.f, 0.f, 0.f, 0.f};
            acc[i][j] = z;
        }

    for (int pass = 0; pass < 2; ++pass) {
        const unsigned short* Ap = (pass == 0) ? A1 : A2;
        if (Ap == nullptr) break;
        const unsigned short* Wp = (pass == 0) ? W1 : W2;
        const int lda = (pass == 0) ? lda1 : lda2;
        const int K   = (pass == 0) ? K1 : K2;
        const int nch = K >> 5;

        for (int c = 0; c < nch; ++c) {
            const int kb = c * 32;
            __syncthreads();   // prior chunk's frags consumed
#pragma unroll
            for (int p = 0; p < 2; ++p) {
                int s = p * 256 + tid;             // 16B slot index 0..511
                int r = s >> 2;                    // tile row
                int q = (r & 3) ^ ((r >> 2) & 3);
                int c8 = ((s & 3) ^ q) * 8;        // swizzled global chunk
                int m = m0 + r;
                if (m >= M) m = M - 1;
                int ldsbase = (p * 256 + wv * 64) * 8;   // wave-uniform
                gload16(Ap + (size_t)m * lda + kb + c8, &As[ldsbase]);
                gload16(Wp + (size_t)(n0 + r) * K + kb + c8, &Wsh[ldsbase]);
            }
            __syncthreads();   // drains vmcnt before barrier

            bf16x8_t af[4], wf[4];
#pragma unroll
            for (int i = 0; i < 4; ++i)
                af[i] = *(const bf16x8_t*)&As[(wm * 64 + i * 16 + lr) * 32 + kslot];
#pragma unroll
            for (int j = 0; j < 4; ++j)
                wf[j] = *(const bf16x8_t*)&Wsh[(wn * 64 + j * 16 + lr) * 32 + kslot];
#pragma unroll
            for (int i = 0; i < 4; ++i)
#pragma unroll
                for (int j = 0; j < 4; ++j)
                    acc[i][j] = __builtin_amdgcn_mfma_f32_16x16x32_bf16(
                        af[i], wf[j], acc[i][j], 0, 0, 0);
        }
    }

    const int lq = lane >> 4;
#pragma unroll
    for (int j = 0; j < 4; ++j) {
        int col = n0 + wn * 64 + j * 16 + lr;
        float bj = 0.f;
        if (b1) bj += b1[col];
        if (b2) bj += b2[col];
#pragma unroll
        for (int i = 0; i < 4; ++i) {
            int rowBase = m0 + wm * 64 + i * 16 + lq * 4;
#pragma unroll
            for (int r = 0; r < 4; ++r) {
                int gm = rowBase + r;
                if (gm >= M) continue;
                float v = acc[i][j][r] + bj;
                if (outbf) {
                    ((unsigned short*)C)[(size_t)gm * ldc + col] = f2bf(v);
                } else {
                    ((float*)C)[(size_t)gm * ldc + col] = v;
                }
            }
        }
    }
}

// ---------------------------------------------------------------------------
extern "C" void kernel_launch(void* const* d_in, const int* in_sizes, int n_in,
                              void* d_out, int out_size, void* d_ws, size_t ws_size,
                              hipStream_t stream) {
    const float* x    = (const float*)d_in[0];
    const float* xb   = (const float*)d_in[1];
    const float* u    = (const float*)d_in[2];
    const int*   ei   = (const int*)d_in[3];
    const int*   eb   = (const int*)d_in[4];
    const int*   ec   = (const int*)d_in[5];
    const int*   bidx = (const int*)d_in[6];
    const int*   cidx = (const int*)d_in[7];
    const float* W_ii = (const float*)d_in[8];   const float* b_ii = (const float*)d_in[9];
    const float* W_bi = (const float*)d_in[10];  const float* b_bi = (const float*)d_in[11];
    const float* W_ci = (const float*)d_in[12];  const float* b_ci = (const float*)d_in[13];
    const float* W_bb = (const float*)d_in[14];  const float* b_bb = (const float*)d_in[15];
    const float* W_cc = (const float*)d_in[16];  const float* b_cc = (const float*)d_in[17];
    const float* W_im = (const float*)d_in[18];  const float* b_im = (const float*)d_in[19];
    const float* W_is = (const float*)d_in[20];  const float* b_is = (const float*)d_in[21];
    const float* W_bm = (const float*)d_in[22];  const float* b_bm = (const float*)d_in[23];
    const float* W_bs = (const float*)d_in[24];  const float* b_bs = (const float*)d_in[25];
    const float* W_cm = (const float*)d_in[26];  const float* b_cm = (const float*)d_in[27];
    const float* W_cs = (const float*)d_in[28];  const float* b_cs = (const float*)d_in[29];

    float* out = (float*)d_out;
    unsigned short* bfr = (unsigned short*)d_ws;

    // ---- ws layout (ushort offsets); total ~99.3 MB ----
    unsigned short* x_bf  = bfr;                 //  6,400,000
    unsigned short* xb_bf = bfr + 6400000;       //  2,560,000
    unsigned short* u_bf  = bfr + 8960000;       //    640,000
    unsigned short* Yx    = bfr + 9600000;       // 25,600,000  [50000 x 512]
    unsigned short* Yxb   = bfr + 35200000;      //  5,120,000  [20000 x 256]
    unsigned short* Yu    = bfr + 40320000;      //  2,560,000  [10000 x 256]
    unsigned short* agg   = bfr + 42880000;      //  6,400,000  [50000 x 128]
    unsigned short* wbuf  = bfr + 49280000;      //    294,912
    float* bias  = (float*)(bfr + 49600000);     //  1024 fp32
    float* bias_x  = bias;
    float* bias_xb = bias + 512;
    float* bias_u  = bias + 768;

    enum {
        O_WX  = 0,       O_WXB = 65536,  O_WU  = 98304,
        O_wis = 114688,  O_wim = 147456, O_wbs = 180224,
        O_wbm = 212992,  O_wcs = 245760, O_wcm = 262144
    };

    // ---- int scratch in d_out boundary region (overwritten by final GEMM) ----
    int* I       = (int*)(out + (size_t)NI * 256);
    int* ci      = I;
    int* cb      = I + 50000;
    int* cc      = I + 100000;
    int* offsets = I + 150000;
    int* cursor  = I + 200000;
    int* bsum    = I + 250000;   // 256
    int* ebase   = I + 250256;   // 256
    int* eids    = I + 250512;   // 530000

    // ---- 1. fused prep (conv + weight pack + zero counts + bias) ----
    WJobs JB;
    auto setj = [&](int i, const float* s, int st, int o, int o2, int N, int K, int d) {
        JB.j[i].src = s; JB.j[i].stride = st; JB.j[i].off = o; JB.j[i].off2 = o2;
        JB.j[i].N = N; JB.j[i].K = K; JB.j[i].dstOff = d;
    };
    setj(0,  W_ii, 256, 0,   -1, 128, 128, O_WX);           // A slice
    setj(1,  W_ii, 256, 128, -1, 128, 128, O_WX + 16384);   // Bii
    setj(2,  W_bi, 256, 128, -1, 128, 128, O_WX + 32768);   // Bbi
    setj(3,  W_ci, 192, 64,  -1, 128, 128, O_WX + 49152);   // Bci
    setj(4,  W_bi, 256, 0,   -1, 128, 128, O_WXB);          // xbp
    setj(5,  W_bb, 256, 0,  128, 128, 128, O_WXB + 16384);  // sb (A+B)
    setj(6,  W_ci, 192, 0,   -1, 128, 64,  O_WU);           // ucp
    setj(7,  W_cc, 128, 0,   64, 128, 64,  O_WU + 8192);    // sc (A+B)
    setj(8,  W_is, 128, 0,   -1, 256, 128, O_wis);
    setj(9,  W_im, 128, 0,   -1, 256, 128, O_wim);
    setj(10, W_bs, 128, 0,   -1, 256, 128, O_wbs);
    setj(11, W_bm, 128, 0,   -1, 256, 128, O_wbm);
    setj(12, W_cs, 64,  0,   -1, 256, 64,  O_wcs);
    setj(13, W_cm, 128, 0,   -1, 256, 128, O_wcm);
    prep_kernel<<<dim3(PREP_NB), dim3(256), 0, stream>>>(
        (const float4*)x, (const float4*)xb, (const float4*)u,
        (ushort4*)x_bf, (ushort4*)xb_bf, (ushort4*)u_bf,
        JB, wbuf, ci, b_ii, b_bi, b_ci, b_bb, b_cc, bias);

    // ---- 2. counts + parallel scan + CSR fill ----
    count_kernel<<<dim3((E_TOT + 255) / 256), dim3(256), 0, stream>>>(
        ei, eb, ec, bidx, cidx, ci, cb, cc);
    scan1_kernel<<<dim3(SCAN_NB), dim3(256), 0, stream>>>(ci, cb, cc, bsum);
    scan2_kernel<<<dim3(1), dim3(256), 0, stream>>>(bsum, ebase);
    scan3_kernel<<<dim3(SCAN_NB), dim3(256), 0, stream>>>(ci, cb, cc, ebase,
                                                          offsets, cursor);
    fill_kernel<<<dim3((E_TOT + 255) / 256), dim3(256), 0, stream>>>(
        ei, eb, ec, bidx, cidx, cursor, eids);

    auto G = [&](const unsigned short* A1, int lda1, int K1, const unsigned short* W1,
                 const unsigned short* A2, int lda2, int K2, const unsigned short* W2,
                 const float* bb1, const float* bb2, int outbf,
                 void* C, int M, int N, int ldc) {
        mfma_gemm_kernel<<<dim3((M + 127) / 128, N / 128), dim3(256), 0, stream>>>(
            A1, lda1, K1, W1, A2, lda2, K2, W2, bb1, bb2, outbf, C, M, ldc);
    };

    // ---- 3. stacked forward GEMMs (biases folded per-column) ----
    G(x_bf, 128, 128, wbuf + O_WX, nullptr, 0, 0, nullptr,
      bias_x, nullptr, 1, Yx, NI, 512, 512);
    G(xb_bf, 128, 128, wbuf + O_WXB, nullptr, 0, 0, nullptr,
      bias_xb, nullptr, 1, Yxb, E_BN, 256, 256);
    G(u_bf, 64, 64, wbuf + O_WU, nullptr, 0, 0, nullptr,
      bias_u, nullptr, 1, Yu, E_CN, 256, 256);

    // ---- 4. gather: base from Y slices + CSR edge rows -> agg bf16 ----
    gather_kernel<<<dim3((NI * 16 + 255) / 256), dim3(256), 0, stream>>>(
        Yx, Yxb, Yu, offsets, ci, cb, cc, eids, agg);

    // ---- 5. final GEMMs ----
    G(x_bf, 128, 128, wbuf + O_wis, agg, 128, 128, wbuf + O_wim,
      b_is, b_im, 0, out, NI, 256, 256);
    G(xb_bf, 128, 128, wbuf + O_wbs, Yxb + 128, 256, 128, wbuf + O_wbm,
      b_bs, b_bm, 0, out + (size_t)NI * 256, E_BN, 256, 256);
    G(u_bf, 64, 64, wbuf + O_wcs, Yu + 128, 256, 128, wbuf + O_wcm,
      b_cs, b_cm, 0, out + (size_t)(NI + E_BN) * 256, E_CN, 256, 256);
}